// Round 5
// baseline (327.694 us; speedup 1.0000x reference)
//
#include <hip/hip_runtime.h>
#include <hip/hip_bf16.h>

// ---------------------------------------------------------------------------
// TokenDiscrepancyLoss: loss = 0.1 * sum_{mask} [ (||t||^2 + sum_c p_c (||c||^2 - 2 t.c)) / H ]
// with p = softmax(hs @ W + b) over C=8192.
//
// R11: k_dual kept byte-identical to R10 (147 us, MX fp8, BK=128). The ~179 us
// prep slice is rebuilt: k_compact (32 blk) + k_prep_all (4096 balanced
// blocks; one 32KB->8KB chunk each for W/cb/hs/tg). Chunk converter reads
// 4 rows x 256 B contiguous per wave (coalesced), packs fp8 in-register,
// stores 4B to LDS in slab order, then coalesced 8 KB copy-out. csq/tsq by
// 16-lane shfl reduction + 1 atomic/row/chunk.
// Dispatches: memset, k_compact, k_prep_all, k_dual, k_merge (5 total).
// ---------------------------------------------------------------------------

#define H        1024
#define CBN      8192
#define NTOK     8192
#define MT       128
#define NTILE    128
#define NKC2     8                // H / 128
#define NCHK     128              // partial strips (one per 64-col wave tile)
#define LOSSW    0.1f
#define CTC      1024.0f          // centering for bf16 ct registers
#define WSCALE   16.0f            // W pre-scale (pow2) for fp8 range
#define SB_UNIT  127              // e8m0 scale = 2^0
#define SB_W     123              // e8m0 scale = 2^-4 (undoes WSCALE)
#define SLAB     131072           // bytes per 128-row panel: 16kc*8KB

typedef __attribute__((ext_vector_type(4)))  int   i32x4;
typedef __attribute__((ext_vector_type(8)))  int   i32x8;
typedef __attribute__((ext_vector_type(16))) float f32x16;

__device__ __forceinline__ unsigned short f2bf(float f) {
  union { float f; unsigned u; } x; x.f = f;
  return (unsigned short)((x.u + 0x7FFFu + ((x.u >> 16) & 1u)) >> 16); // RNE
}
__device__ __forceinline__ float bf2f(unsigned short u) {
  union { unsigned u; float f; } x; x.u = (unsigned)u << 16;
  return x.f;
}

// ---- fp32 -> fp8 e4m3fn (OCP) ----
__device__ unsigned char f2fp8_sw(float f) {
  float a = fabsf(f);
  unsigned s = f < 0.f ? 0x80u : 0u;
  if (!(a < 448.f)) return (unsigned char)(s | 0x7Eu);
  if (a < 0.0009765625f) return (unsigned char)s;
  int e; float m = frexpf(a, &e);
  int te = e - 1;
  if (te < -6) {
    int q = (int)rintf(a * 512.f); if (q > 7) q = 7;
    return (unsigned char)(s | q);
  }
  int q = (int)rintf((2.f * m - 1.f) * 8.f);
  int E = te + 7, M = q;
  if (q == 8) { E += 1; M = 0; }
  if (E > 15) return (unsigned char)(s | 0x7Eu);
  return (unsigned char)(s | (E << 3) | M);
}
__device__ __forceinline__ unsigned pack4(float a, float b, float c, float d) {
#if __has_builtin(__builtin_amdgcn_cvt_pk_fp8_f32)
  int r = __builtin_amdgcn_cvt_pk_fp8_f32(a, b, 0, false);
  r     = __builtin_amdgcn_cvt_pk_fp8_f32(c, d, r, true);
  return (unsigned)r;
#else
  return (unsigned)f2fp8_sw(a) | ((unsigned)f2fp8_sw(b) << 8) |
         ((unsigned)f2fp8_sw(c) << 16) | ((unsigned)f2fp8_sw(d) << 24);
#endif
}

// kc-chunk internal offset for (row c, local k octet g in [0,8)):
//   half = g>>2 (k>>5), b4 = (g>>1)&1 ((k>>4)&1), lo8 = (g&1)*8 (k&8)
//   off  = half*4096 + b4*2048 + c*16 + lo8
__device__ __forceinline__ int slab_off(int g, int c) {
  return ((g >> 2) << 12) + (((g >> 1) & 1) << 11) + (c << 4) + ((g & 1) << 3);
}

// async global->LDS DMA, 16B/lane; LDS dest = wave-uniform base + lane*16
__device__ __forceinline__ void load_lds16(const void* g, void* l) {
  __builtin_amdgcn_global_load_lds((const __attribute__((address_space(1))) void*)g,
                                   (__attribute__((address_space(3))) void*)l,
                                   16, 0, 0);
}
__device__ __forceinline__ void wait_vm8() { asm volatile("s_waitcnt vmcnt(8)" ::: "memory"); }
__device__ __forceinline__ void wait_vm0() { asm volatile("s_waitcnt vmcnt(0)" ::: "memory"); }
__device__ __forceinline__ void barrier_raw() { asm volatile("s_barrier" ::: "memory"); }

// XCD-aware tile mapping
__device__ __forceinline__ void tile_map(int* tilex, int* tiley) {
  const int flat = blockIdx.y * 64 + blockIdx.x;
  const int xcd = flat & 7, loc = flat >> 3;
  *tiley = xcd * 8 + (loc & 7);
  *tilex = loc >> 3;
}

// ---------------- k_compact: image-token mask -> compacted index list ------
__global__ __launch_bounds__(256) void k_compact(
    const int* __restrict__ ids, int* __restrict__ list,
    int* __restrict__ counter) {
  const int b = blockIdx.x, t = threadIdx.x;
  int f = 0;
  #pragma unroll
  for (int j = 0; j < 16; ++j) f |= ids[2 * (t * 16 + j) + 1];
  int anyodd = __syncthreads_or(f);
  int i = b * 256 + t;
  int v = anyodd ? ids[i] : ids[2 * i];
  bool act = (v == 1);
  unsigned long long mask = __ballot(act);
  int lane = t & 63;
  int base = 0;
  if (lane == 0) base = atomicAdd(counter, __popcll(mask));
  base = __shfl(base, 0);
  if (act) list[base + __popcll(mask & ((1ull << lane) - 1ull))] = i;
}

// -------- k_prep_all: 4096 balanced chunk blocks -> fp8 slabs + csq/tsq ----
// b in [0,1024): W (tiley=b>>4, kc=b&15)   [col-major source, as before]
// b in [1024,2048): cb chunk  + csq partials
// b in [2048,3072): hs chunk (gathered rows)
// b in [3072,4096): tg chunk (gathered rows) + tsq partials
// Chunk converter: per rr (8 iters), wave reads 4 rows x 256 B contiguous;
// thread (sub=t>>4, kq=t&15) covers row c=rr*16+sub, k quarter-octet kq.
__global__ __launch_bounds__(256) void k_prep_all(
    const float* __restrict__ hs, const float* __restrict__ tg,
    const float* __restrict__ cb, const float* __restrict__ W,
    const int* __restrict__ list, const int* __restrict__ counter,
    float* __restrict__ csq, float* __restrict__ tsq,
    unsigned char* __restrict__ Wtb, unsigned char* __restrict__ Cbb,
    unsigned char* __restrict__ Ahs, unsigned char* __restrict__ Atg) {
  __shared__ __align__(16) unsigned char tile[8192];
  __shared__ int stok[128];
  const int b = blockIdx.x, t = threadIdx.x;

  if (b < 1024) {
    // W [H][C] fp32 -> fp8 slab [tiley][kc][half][b4][c][16], scaled x16
    const int tiley = b >> 4, kc = b & 15;
    const int c = t & 127, gh = t >> 7;
    unsigned char* dst = Wtb + (size_t)tiley * SLAB + (size_t)kc * 8192;
    #pragma unroll
    for (int gi = 0; gi < 4; ++gi) {
      const int g = gh * 4 + gi;
      const float* wp = W + (size_t)(kc * 64 + g * 8) * CBN + tiley * 128 + c;
      float v[8];
      #pragma unroll
      for (int j = 0; j < 8; ++j) v[j] = wp[(size_t)j * CBN] * WSCALE;
      uint2 pk;
      pk.x = pack4(v[0], v[1], v[2], v[3]);
      pk.y = pack4(v[4], v[5], v[6], v[7]);
      *(uint2*)(dst + slab_off(g, c)) = pk;
    }
    return;
  }

  const int sub = t >> 4, kq = t & 15;
  const int g = kq >> 1;
  // byte offset within chunk, minus the c*16 term; +4B for odd quarter
  const int toff = ((g >> 2) << 12) + (((g >> 1) & 1) << 11) + ((g & 1) << 3)
                 + ((kq & 1) << 2);

  if (b < 2048) {
    // codebook [C][H] fp32 -> fp8 chunk + csq partials
    const int idx = b - 1024, tiley = idx >> 4, kc = idx & 15;
    #pragma unroll
    for (int rr = 0; rr < 8; ++rr) {
      const int c = rr * 16 + sub;
      const float4 v = *(const float4*)(cb + (size_t)(tiley * 128 + c) * H
                                        + kc * 64 + kq * 4);
      float sq = v.x * v.x + v.y * v.y + v.z * v.z + v.w * v.w;
      sq += __shfl_xor(sq, 1); sq += __shfl_xor(sq, 2);
      sq += __shfl_xor(sq, 4); sq += __shfl_xor(sq, 8);
      if (kq == 0) atomicAdd(&csq[tiley * 128 + c], sq);
      *(unsigned*)&tile[toff + c * 16] = pack4(v.x, v.y, v.z, v.w);
    }
    __syncthreads();
    const uint4* tp = (const uint4*)tile;
    uint4 x0 = tp[t * 2], x1 = tp[t * 2 + 1];
    unsigned char* dst = Cbb + (size_t)tiley * SLAB + (size_t)kc * 8192 + t * 32;
    *(uint4*)dst = x0; *(uint4*)(dst + 16) = x1;
    return;
  }

  // gathered token chunks (hs or tg)
  const bool is_tg = (b >= 3072);
  const int idx = (b - 2048) & 1023, tilex = idx >> 4, kc = idx & 15;
  const int n = *counter;
  const int n_pad = (n + MT - 1) & ~(MT - 1);
  if (tilex * MT >= n_pad) return;
  if (t < 128) {
    int ga = tilex * MT + t;
    stok[t] = list[(ga < n) ? ga : 0];
  }
  __syncthreads();
  const float* src = is_tg ? tg : hs;
  #pragma unroll
  for (int rr = 0; rr < 8; ++rr) {
    const int c = rr * 16 + sub;
    const float4 v = *(const float4*)(src + (size_t)stok[c] * H
                                      + kc * 64 + kq * 4);
    if (is_tg) {
      float sq = v.x * v.x + v.y * v.y + v.z * v.z + v.w * v.w;
      sq += __shfl_xor(sq, 1); sq += __shfl_xor(sq, 2);
      sq += __shfl_xor(sq, 4); sq += __shfl_xor(sq, 8);
      if (kq == 0) atomicAdd(&tsq[tilex * MT + c], sq);
    }
    *(unsigned*)&tile[toff + c * 16] = pack4(v.x, v.y, v.z, v.w);
  }
  __syncthreads();
  const uint4* tp = (const uint4*)tile;
  uint4 x0 = tp[t * 2], x1 = tp[t * 2 + 1];
  unsigned char* dst = (is_tg ? Atg : Ahs)
                     + (size_t)tilex * SLAB + (size_t)kc * 8192 + t * 32;
  *(uint4*)dst = x0; *(uint4*)(dst + 16) = x1;
}

// per-wave DMA batch for one BK=128 stage: 16 KB contiguous per operand
// (2 slab chunks); wave w covers rows {w, w+4, w+8, w+12} x 1 KB of each.
// 8 loads/wave total (4 A + 4 B) -> wait vmcnt(8) drains the previous stage.
#define ISSUE2(Aslab, Bslab, kc2, pb)                                       \
  do {                                                                      \
    const unsigned char* ap_ = (Aslab) + Aoff + (size_t)(kc2) * 16384 + lane * 16; \
    const unsigned char* bp_ = (Bslab) + Boff + (size_t)(kc2) * 16384 + lane * 16; \
    _Pragma("unroll")                                                       \
    for (int q_ = 0; q_ < 4; ++q_) {                                        \
      load_lds16(ap_ + (w + 4 * q_) * 1024, &sA[pb][(w + 4 * q_) * 1024]);  \
      load_lds16(bp_ + (w + 4 * q_) * 1024, &sB[pb][(w + 4 * q_) * 1024]);  \
    }                                                                       \
  } while (0)

// one BK=128 compute step: 2 sub-chunks x 4 MX-scaled 32x32x64 fp8 MFMA.
// Per-lane operand: 32 contiguous k-bytes = one MX block:
//   row = lane&31, k = (lane>>5)*32 + [0..31]
// -> two conflict-free stride-16B ds_read_b128 (b4=0 at +0, b4=1 at +2048).
#define COMPUTE_KC2(cur, SB)                                                \
  do {                                                                      \
    _Pragma("unroll")                                                       \
    for (int s_ = 0; s_ < 2; ++s_) {                                        \
      const unsigned char* abase = &sA[cur][s_ * 8192 + rb];                \
      const unsigned char* bbase = &sB[cur][s_ * 8192 + rb];                \
      i32x8 aF[2], bF[2];                                                   \
      _Pragma("unroll")                                                     \
      for (int mi = 0; mi < 2; ++mi) {                                      \
        i32x4 lo = *(const i32x4*)(abase + ((wr * 64 + mi * 32) << 4));     \
        i32x4 hh = *(const i32x4*)(abase + ((wr * 64 + mi * 32) << 4) + 2048); \
        aF[mi] = __builtin_shufflevector(lo, hh, 0, 1, 2, 3, 4, 5, 6, 7);   \
      }                                                                     \
      _Pragma("unroll")                                                     \
      for (int ni = 0; ni < 2; ++ni) {                                      \
        i32x4 lo = *(const i32x4*)(bbase + ((wc * 64 + ni * 32) << 4));     \
        i32x4 hh = *(const i32x4*)(bbase + ((wc * 64 + ni * 32) << 4) + 2048); \
        bF[ni] = __builtin_shufflevector(lo, hh, 0, 1, 2, 3, 4, 5, 6, 7);   \
      }                                                                     \
      _Pragma("unroll")                                                     \
      for (int mi = 0; mi < 2; ++mi)                                        \
        _Pragma("unroll")                                                   \
        for (int ni = 0; ni < 2; ++ni)                                      \
          acc[mi][ni] = __builtin_amdgcn_mfma_scale_f32_32x32x64_f8f6f4(    \
              aF[mi], bF[ni], acc[mi][ni], 0, 0, 0, SB_UNIT, 0, (SB));      \
    }                                                                       \
  } while (0)

// ---------- dual-phase GEMM: cross (ct -> regs) then logits+softmax --------
__global__ __launch_bounds__(256, 2) void k_dual(
    const unsigned char* __restrict__ Atg, const unsigned char* __restrict__ Cbb,
    const unsigned char* __restrict__ Ahs, const unsigned char* __restrict__ Wtb,
    const float* __restrict__ csq, const float* __restrict__ bias,
    const int* __restrict__ counter,
    float* __restrict__ pm, float* __restrict__ pl, float* __restrict__ ps) {
  const int n = *counter;
  int tilex, tiley;
  tile_map(&tilex, &tiley);
  if (tilex * MT >= n) return;

  __shared__ __align__(16) unsigned char sA[2][16384];
  __shared__ __align__(16) unsigned char sB[2][16384];

  const int t = threadIdx.x;
  const int w = t >> 6, lane = t & 63;
  const int wr = w >> 1, wc = w & 1;
  const int hi32 = lane >> 5, lc32 = lane & 31;
  const int rb = (hi32 << 12) + (lc32 << 4);     // half*4096 + row_lane*16
  const size_t Aoff = (size_t)tilex * SLAB;
  const size_t Boff = (size_t)tiley * SLAB;

  const f32x16 fz = {0.f, 0.f, 0.f, 0.f, 0.f, 0.f, 0.f, 0.f,
                     0.f, 0.f, 0.f, 0.f, 0.f, 0.f, 0.f, 0.f};
  f32x16 acc[2][2];
  #pragma unroll
  for (int mi = 0; mi < 2; ++mi)
    #pragma unroll
    for (int ni = 0; ni < 2; ++ni) acc[mi][ni] = fz;

  // ---------------- phase 1: ct = csq - 2 * (tg x codebook^T) --------------
  // #pragma unroll 1: runtime loop keeps acc a loop-carried phi (full unroll
  // spilled 1.4+ GB/dispatch of operand tuples in R7/R8).
  ISSUE2(Atg, Cbb, 0, 0);
  #pragma unroll 1
  for (int kc = 0; kc < NKC2; ++kc) {
    const int cur = kc & 1;
    if (kc + 1 < NKC2) ISSUE2(Atg, Cbb, kc + 1, cur ^ 1);
    else               ISSUE2(Ahs, Wtb, 0, 0);    // phase-boundary prefetch
    wait_vm8();
    barrier_raw();
    COMPUTE_KC2(cur, SB_UNIT);
    barrier_raw();
  }

  // pack ct into bf16-pair registers (no memory round trip)
  unsigned ctp[2][2][8];
  {
    float cqc[2];
    #pragma unroll
    for (int ni = 0; ni < 2; ++ni)
      cqc[ni] = csq[tiley * NTILE + wc * 64 + ni * 32 + lc32] - CTC;
    #pragma unroll
    for (int mi = 0; mi < 2; ++mi)
      #pragma unroll
      for (int ni = 0; ni < 2; ++ni) {
        #pragma unroll
        for (int rp = 0; rp < 8; ++rp) {
          const float v0 = cqc[ni] - 2.f * acc[mi][ni][2 * rp];
          const float v1 = cqc[ni] - 2.f * acc[mi][ni][2 * rp + 1];
          ctp[mi][ni][rp] = (unsigned)f2bf(v0) | ((unsigned)f2bf(v1) << 16);
        }
        acc[mi][ni] = fz;
      }
  }

  // ---------------- phase 2: logits = hs x W^T (W scale folded as 2^-4) ----
  #pragma unroll 1
  for (int kc = 0; kc < NKC2; ++kc) {
    const int cur = kc & 1;
    if (kc + 1 < NKC2) { ISSUE2(Ahs, Wtb, kc + 1, cur ^ 1); wait_vm8(); }
    else               { wait_vm0(); }
    barrier_raw();
    COMPUTE_KC2(cur, SB_W);
    barrier_raw();
  }

  // ---------------- fused softmax epilogue per 64-col strip ----------------
  float bv[2];
  #pragma unroll
  for (int ni = 0; ni < 2; ++ni)
    bv[ni] = bias[tiley * NTILE + wc * 64 + ni * 32 + lc32];

  const int chunk = tiley * 2 + wc;
  #pragma unroll
  for (int mi = 0; mi < 2; ++mi) {
    #pragma unroll
    for (int r = 0; r < 16; ++r) {
      float lg[2], ct[2];
      #pragma unroll
      for (int ni = 0; ni < 2; ++ni) {
        lg[ni] = acc[mi][ni][r] + bv[ni];
        ct[ni] = bf2f((unsigned short)((ctp[mi][ni][r >> 1] >> ((r & 1) * 16)) & 0xFFFFu));
      }
      float tmax = fmaxf(lg[0], lg[1]);
      #pragma unroll
      for (int d = 1; d < 32; d <<= 1) tmax = fmaxf(tmax, __shfl_xor(tmax, d));
      float le = 0.f, se = 0.f;
      #pragma unroll
      for (int ni = 0; ni < 2; ++ni) {
        const float e = __expf(lg[ni] - tmax);
        le += e; se += e * ct[ni];
      }
      #pragma unroll
      for (int d = 1; d < 32; d <<= 1) {
        le += __shfl_xor(le, d);
        se += __shfl_xor(se, d);
      }
      if (lc32 == 0) {
        // 32x32 C/D: row = (r&3) + 8*(r>>2) + 4*(lane>>5), col = lane&31
        const int row = tilex * MT + wr * 64 + mi * 32 + 4 * hi32 + (r & 3) + 8 * (r >> 2);
        pm[chunk * NTOK + row] = tmax;
        pl[chunk * NTOK + row] = le;
        ps[chunk * NTOK + row] = se;
      }
    }
  }
}

// -------- merge strip partials -> scalar loss (last block finalizes) -------
// 128 blocks: 64 tokens x 4 strip-quarters per block; softmax partials
// (M,L,S) merge associatively: M=max Mi; L=sum Li e^{Mi-M}; S likewise.
__global__ __launch_bounds__(256) void k_merge(
    const int* __restrict__ counter, const float* __restrict__ tsq,
    const float* __restrict__ pm, const float* __restrict__ pl,
    const float* __restrict__ ps, float* __restrict__ lsum,
    int* __restrict__ done, float* __restrict__ out) {
  const int n = *counter;
  const int tl = threadIdx.x & 63, jq = threadIdx.x >> 6;
  const int ga = blockIdx.x * 64 + tl;
  float M = -1e30f, L = 0.f, S = 0.f;
  #pragma unroll 4
  for (int j = jq * 32; j < jq * 32 + 32; ++j) M = fmaxf(M, pm[j * NTOK + ga]);
  #pragma unroll 4
  for (int j = jq * 32; j < jq * 32 + 32; ++j) {
    const float e = __expf(pm[j * NTOK + ga] - M);
    L += pl[j * NTOK + ga] * e;
    S += ps[j * NTOK + ga] * e;
  }
  __shared__ float sM[4][64], sL[4][64], sS[4][64];
  sM[jq][tl] = M; sL[jq][tl] = L; sS[jq][tl] = S;
  __syncthreads();
  if (jq == 0) {
    float Mm = fmaxf(fmaxf(sM[0][tl], sM[1][tl]), fmaxf(sM[2][tl], sM[3][tl]));
    float Lt = 0.f, St = 0.f;
    #pragma unroll
    for (int q = 0; q < 4; ++q) {
      const float e = __expf(sM[q][tl] - Mm);
      Lt += sL[q][tl] * e;
      St += sS[q][tl] * e;
    }
    float val = 0.f;
    if (ga < n) val = (tsq[ga] + CTC + St / Lt) * (LOSSW / (float)H);
    #pragma unroll
    for (int d = 1; d < 64; d <<= 1) val += __shfl_xor(val, d);
    if (tl == 0) {
      atomicAdd(lsum, val);
      __threadfence();
      const int tk = atomicAdd(done, 1);
      if (tk == (int)gridDim.x - 1) {
        __threadfence();
        out[0] = atomicAdd(lsum, 0.0f);   // atomic read-back = final sum
      }
    }
  }
}

// ---------------------------------------------------------------------------
extern "C" void kernel_launch(void* const* d_in, const int* in_sizes, int n_in,
                              void* d_out, int out_size, void* d_ws, size_t ws_size,
                              hipStream_t stream) {
  const float* hs   = (const float*)d_in[0];
  const int*   ids  = (const int*)d_in[1];
  const float* tg   = (const float*)d_in[2];
  const float* cb   = (const float*)d_in[3];
  const float* W    = (const float*)d_in[4];
  const float* bias = (const float*)d_in[5];

  char* ws = (char*)d_ws;
  constexpr size_t OFF_CSQ  = 0;                       // f32[8192] (zeroed)
  constexpr size_t OFF_TSQ  = 32768;                   // f32[8192] (zeroed)
  constexpr size_t OFF_CNT  = 65536;                   // int (zeroed)
  constexpr size_t OFF_DONE = 65540;                   // int (zeroed)
  constexpr size_t OFF_LSUM = 65544;                   // f32 (zeroed)
  constexpr size_t ZERO_BYTES = 65548;
  constexpr size_t OFF_LIST = 65664;                   // int[8192]
  constexpr size_t OFF_AHS  = 98432;                   // fp8 slab 8 MiB
  constexpr size_t OFF_ATG  = OFF_AHS + (size_t)NTOK * H;
  constexpr size_t OFF_WTB  = OFF_ATG + (size_t)NTOK * H;
  constexpr size_t OFF_CBB  = OFF_WTB + (size_t)CBN * H;
  constexpr size_t OFF_PM   = OFF_CBB + (size_t)CBN * H;
  constexpr size_t OFF_PL   = OFF_PM + (size_t)NCHK * NTOK * 4;
  constexpr size_t OFF_PS   = OFF_PL + (size_t)NCHK * NTOK * 4;

  float*          csq  = (float*)(ws + OFF_CSQ);
  float*          tsq  = (float*)(ws + OFF_TSQ);
  int*            cnt  = (int*)(ws + OFF_CNT);
  int*            done = (int*)(ws + OFF_DONE);
  float*          lsum = (float*)(ws + OFF_LSUM);
  int*            list = (int*)(ws + OFF_LIST);
  unsigned char*  Ahs  = (unsigned char*)(ws + OFF_AHS);
  unsigned char*  Atg  = (unsigned char*)(ws + OFF_ATG);
  unsigned char*  Wtb  = (unsigned char*)(ws + OFF_WTB);
  unsigned char*  Cbb  = (unsigned char*)(ws + OFF_CBB);
  float*          pm   = (float*)(ws + OFF_PM);
  float*          pl   = (float*)(ws + OFF_PL);
  float*          ps   = (float*)(ws + OFF_PS);

  hipMemsetAsync(ws, 0, ZERO_BYTES, stream);

  k_compact<<<32, 256, 0, stream>>>(ids, list, cnt);
  k_prep_all<<<4096, 256, 0, stream>>>(hs, tg, cb, W, list, cnt, csq, tsq,
                                       Wtb, Cbb, Ahs, Atg);
  k_dual<<<dim3(64, 64), 256, 0, stream>>>(Atg, Cbb, Ahs, Wtb, csq, bias, cnt,
                                           pm, pl, ps);
  k_merge<<<NTOK / 64, 256, 0, stream>>>(cnt, tsq, pm, pl, ps, lsum, done,
                                         (float*)d_out);
}

// Round 7
// 308.878 us; speedup vs baseline: 1.0609x; 1.0609x over previous
//
#include <hip/hip_runtime.h>
#include <hip/hip_bf16.h>

// ---------------------------------------------------------------------------
// TokenDiscrepancyLoss: loss = 0.1 * sum_{mask} [ (||t||^2 + sum_c p_c (||c||^2 - 2 t.c)) / H ]
// with p = softmax(hs @ W + b) over C=8192.
//
// R13: R12's 128 MiB ct buffer likely overran the workspace (container
// fault) -> back to the proven ~46 MiB footprint (R11 layout, no ct).
// k_dual restructured per T4 (counted vmcnt, never drain): 3 LDS buffers
// (48 KB -> 3 blocks/CU), 2-stage-ahead prefetch, unified 32-stage loop
// over both GEMM phases (stage<16: tg x cb^T with scale 2^0; else hs x W^T
// with scale 2^-4; ctp pack at the boundary). Per-stage wait drops from a
// full L2/L3 round trip (R9/R10: 1-deep, full drain -> 147-156 us) to ~0.
// Everything else byte-identical to R11 (absmax 0.0 proven).
// Dispatches: memset, k_compact, k_prep_all, k_dual, k_merge (5 total).
// ---------------------------------------------------------------------------

#define H        1024
#define CBN      8192
#define NTOK     8192
#define MT       128
#define NTILE    128
#define NKC      16               // H / 64 kc-chunks per phase
#define NSTG     32               // unified stages = 2 * NKC
#define NCHK     128              // partial strips (one per 64-col wave tile)
#define LOSSW    0.1f
#define CTC      1024.0f          // centering for bf16 ct registers
#define WSCALE   16.0f            // W pre-scale (pow2) for fp8 range
#define SB_UNIT  127              // e8m0 scale = 2^0
#define SB_W     123              // e8m0 scale = 2^-4 (undoes WSCALE)
#define SLAB     131072           // bytes per 128-row panel: 16kc*8KB

typedef __attribute__((ext_vector_type(4)))  int   i32x4;
typedef __attribute__((ext_vector_type(8)))  int   i32x8;
typedef __attribute__((ext_vector_type(16))) float f32x16;

__device__ __forceinline__ unsigned short f2bf(float f) {
  union { float f; unsigned u; } x; x.f = f;
  return (unsigned short)((x.u + 0x7FFFu + ((x.u >> 16) & 1u)) >> 16); // RNE
}
__device__ __forceinline__ float bf2f(unsigned short u) {
  union { unsigned u; float f; } x; x.u = (unsigned)u << 16;
  return x.f;
}

// ---- fp32 -> fp8 e4m3fn (OCP) ----
__device__ unsigned char f2fp8_sw(float f) {
  float a = fabsf(f);
  unsigned s = f < 0.f ? 0x80u : 0u;
  if (!(a < 448.f)) return (unsigned char)(s | 0x7Eu);
  if (a < 0.0009765625f) return (unsigned char)s;
  int e; float m = frexpf(a, &e);
  int te = e - 1;
  if (te < -6) {
    int q = (int)rintf(a * 512.f); if (q > 7) q = 7;
    return (unsigned char)(s | q);
  }
  int q = (int)rintf((2.f * m - 1.f) * 8.f);
  int E = te + 7, M = q;
  if (q == 8) { E += 1; M = 0; }
  if (E > 15) return (unsigned char)(s | 0x7Eu);
  return (unsigned char)(s | (E << 3) | M);
}
__device__ __forceinline__ unsigned pack4(float a, float b, float c, float d) {
#if __has_builtin(__builtin_amdgcn_cvt_pk_fp8_f32)
  int r = __builtin_amdgcn_cvt_pk_fp8_f32(a, b, 0, false);
  r     = __builtin_amdgcn_cvt_pk_fp8_f32(c, d, r, true);
  return (unsigned)r;
#else
  return (unsigned)f2fp8_sw(a) | ((unsigned)f2fp8_sw(b) << 8) |
         ((unsigned)f2fp8_sw(c) << 16) | ((unsigned)f2fp8_sw(d) << 24);
#endif
}

// kc-chunk internal offset for (row c, local k octet g in [0,8)):
//   half = g>>2 (k>>5), b4 = (g>>1)&1 ((k>>4)&1), lo8 = (g&1)*8 (k&8)
__device__ __forceinline__ int slab_off(int g, int c) {
  return ((g >> 2) << 12) + (((g >> 1) & 1) << 11) + (c << 4) + ((g & 1) << 3);
}

// async global->LDS DMA, 16B/lane; LDS dest = wave-uniform base + lane*16
__device__ __forceinline__ void load_lds16(const void* g, void* l) {
  __builtin_amdgcn_global_load_lds((const __attribute__((address_space(1))) void*)g,
                                   (__attribute__((address_space(3))) void*)l,
                                   16, 0, 0);
}
__device__ __forceinline__ void wait_vm8() { asm volatile("s_waitcnt vmcnt(8)" ::: "memory"); }
__device__ __forceinline__ void wait_vm4() { asm volatile("s_waitcnt vmcnt(4)" ::: "memory"); }
__device__ __forceinline__ void wait_vm0() { asm volatile("s_waitcnt vmcnt(0)" ::: "memory"); }
__device__ __forceinline__ void barrier_raw() { asm volatile("s_barrier" ::: "memory"); }

// XCD-aware tile mapping
__device__ __forceinline__ void tile_map(int* tilex, int* tiley) {
  const int flat = blockIdx.y * 64 + blockIdx.x;
  const int xcd = flat & 7, loc = flat >> 3;
  *tiley = xcd * 8 + (loc & 7);
  *tilex = loc >> 3;
}

// ---------------- k_compact: image-token mask -> compacted index list ------
__global__ __launch_bounds__(256) void k_compact(
    const int* __restrict__ ids, int* __restrict__ list,
    int* __restrict__ counter) {
  const int b = blockIdx.x, t = threadIdx.x;
  int f = 0;
  #pragma unroll
  for (int j = 0; j < 16; ++j) f |= ids[2 * (t * 16 + j) + 1];
  int anyodd = __syncthreads_or(f);
  int i = b * 256 + t;
  int v = anyodd ? ids[i] : ids[2 * i];
  bool act = (v == 1);
  unsigned long long mask = __ballot(act);
  int lane = t & 63;
  int base = 0;
  if (lane == 0) base = atomicAdd(counter, __popcll(mask));
  base = __shfl(base, 0);
  if (act) list[base + __popcll(mask & ((1ull << lane) - 1ull))] = i;
}

// -------- k_prep_all: 4096 balanced chunk blocks -> fp8 slabs + csq/tsq ----
__global__ __launch_bounds__(256) void k_prep_all(
    const float* __restrict__ hs, const float* __restrict__ tg,
    const float* __restrict__ cb, const float* __restrict__ W,
    const int* __restrict__ list, const int* __restrict__ counter,
    float* __restrict__ csq, float* __restrict__ tsq,
    unsigned char* __restrict__ Wtb, unsigned char* __restrict__ Cbb,
    unsigned char* __restrict__ Ahs, unsigned char* __restrict__ Atg) {
  __shared__ __align__(16) unsigned char tile[8192];
  __shared__ int stok[128];
  const int b = blockIdx.x, t = threadIdx.x;

  if (b < 1024) {
    // W [H][C] fp32 -> fp8 slab [tiley][kc][half][b4][c][16], scaled x16
    const int tiley = b >> 4, kc = b & 15;
    const int c = t & 127, gh = t >> 7;
    unsigned char* dst = Wtb + (size_t)tiley * SLAB + (size_t)kc * 8192;
    #pragma unroll
    for (int gi = 0; gi < 4; ++gi) {
      const int g = gh * 4 + gi;
      const float* wp = W + (size_t)(kc * 64 + g * 8) * CBN + tiley * 128 + c;
      float v[8];
      #pragma unroll
      for (int j = 0; j < 8; ++j) v[j] = wp[(size_t)j * CBN] * WSCALE;
      uint2 pk;
      pk.x = pack4(v[0], v[1], v[2], v[3]);
      pk.y = pack4(v[4], v[5], v[6], v[7]);
      *(uint2*)(dst + slab_off(g, c)) = pk;
    }
    return;
  }

  const int sub = t >> 4, kq = t & 15;
  const int g = kq >> 1;
  const int toff = ((g >> 2) << 12) + (((g >> 1) & 1) << 11) + ((g & 1) << 3)
                 + ((kq & 1) << 2);

  if (b < 2048) {
    // codebook [C][H] fp32 -> fp8 chunk + csq partials
    const int idx = b - 1024, tiley = idx >> 4, kc = idx & 15;
    #pragma unroll
    for (int rr = 0; rr < 8; ++rr) {
      const int c = rr * 16 + sub;
      const float4 v = *(const float4*)(cb + (size_t)(tiley * 128 + c) * H
                                        + kc * 64 + kq * 4);
      float sq = v.x * v.x + v.y * v.y + v.z * v.z + v.w * v.w;
      sq += __shfl_xor(sq, 1); sq += __shfl_xor(sq, 2);
      sq += __shfl_xor(sq, 4); sq += __shfl_xor(sq, 8);
      if (kq == 0) atomicAdd(&csq[tiley * 128 + c], sq);
      *(unsigned*)&tile[toff + c * 16] = pack4(v.x, v.y, v.z, v.w);
    }
    __syncthreads();
    const uint4* tp = (const uint4*)tile;
    uint4 x0 = tp[t * 2], x1 = tp[t * 2 + 1];
    unsigned char* dst = Cbb + (size_t)tiley * SLAB + (size_t)kc * 8192 + t * 32;
    *(uint4*)dst = x0; *(uint4*)(dst + 16) = x1;
    return;
  }

  // gathered token chunks (hs or tg)
  const bool is_tg = (b >= 3072);
  const int idx = (b - 2048) & 1023, tilex = idx >> 4, kc = idx & 15;
  const int n = *counter;
  const int n_pad = (n + MT - 1) & ~(MT - 1);
  if (tilex * MT >= n_pad) return;
  if (t < 128) {
    int ga = tilex * MT + t;
    stok[t] = list[(ga < n) ? ga : 0];
  }
  __syncthreads();
  const float* src = is_tg ? tg : hs;
  #pragma unroll
  for (int rr = 0; rr < 8; ++rr) {
    const int c = rr * 16 + sub;
    const float4 v = *(const float4*)(src + (size_t)stok[c] * H
                                      + kc * 64 + kq * 4);
    if (is_tg) {
      float sq = v.x * v.x + v.y * v.y + v.z * v.z + v.w * v.w;
      sq += __shfl_xor(sq, 1); sq += __shfl_xor(sq, 2);
      sq += __shfl_xor(sq, 4); sq += __shfl_xor(sq, 8);
      if (kq == 0) atomicAdd(&tsq[tilex * MT + c], sq);
    }
    *(unsigned*)&tile[toff + c * 16] = pack4(v.x, v.y, v.z, v.w);
  }
  __syncthreads();
  const uint4* tp = (const uint4*)tile;
  uint4 x0 = tp[t * 2], x1 = tp[t * 2 + 1];
  unsigned char* dst = (is_tg ? Atg : Ahs)
                     + (size_t)tilex * SLAB + (size_t)kc * 8192 + t * 32;
  *(uint4*)dst = x0; *(uint4*)(dst + 16) = x1;
}

// ---------- dual-phase GEMM, unified 32-stage counted-vmcnt pipeline -------
// Stage s < 16: phase 1 (Atg x Cbb, scale 2^0), kc = s.
// Stage s >= 16: phase 2 (Ahs x Wtb, scale 2^-4), kc = s - 16.
// 3 LDS buffers; stage s lives in buf s%3; iter s issues stage s+2 into
// buf (s+2)%3 (the buffer whose readers passed iter s-1's trailing barrier).
// 4 DMA loads/stage/wave -> vmcnt(8) leaves stages s+1,s+2 in flight.
__global__ __launch_bounds__(256, 2) void k_dual(
    const unsigned char* __restrict__ Atg, const unsigned char* __restrict__ Cbb,
    const unsigned char* __restrict__ Ahs, const unsigned char* __restrict__ Wtb,
    const float* __restrict__ csq, const float* __restrict__ bias,
    const int* __restrict__ counter,
    float* __restrict__ pm, float* __restrict__ pl, float* __restrict__ ps) {
  const int n = *counter;
  int tilex, tiley;
  tile_map(&tilex, &tiley);
  if (tilex * MT >= n) return;

  __shared__ __align__(16) unsigned char sA[3][8192];
  __shared__ __align__(16) unsigned char sB[3][8192];

  const int t = threadIdx.x;
  const int w = t >> 6, lane = t & 63;
  const int wr = w >> 1, wc = w & 1;
  const int hi32 = lane >> 5, lc32 = lane & 31;
  const int rb = (hi32 << 12) + (lc32 << 4);     // half*4096 + row_lane*16
  const size_t Aoff = (size_t)tilex * SLAB;
  const size_t Boff = (size_t)tiley * SLAB;

  // csq prefetch (consumed at the s==16 ctp pack; avoids a mid-loop stall)
  float cqc[2];
  #pragma unroll
  for (int ni = 0; ni < 2; ++ni)
    cqc[ni] = csq[tiley * NTILE + wc * 64 + ni * 32 + lc32] - CTC;

  const f32x16 fz = {0.f, 0.f, 0.f, 0.f, 0.f, 0.f, 0.f, 0.f,
                     0.f, 0.f, 0.f, 0.f, 0.f, 0.f, 0.f, 0.f};
  f32x16 acc[2][2];
  #pragma unroll
  for (int mi = 0; mi < 2; ++mi)
    #pragma unroll
    for (int ni = 0; ni < 2; ++ni) acc[mi][ni] = fz;
  unsigned ctp[2][2][8];

// issue stage ss into buffer nb (4 x 1 KB wave-loads: 2 A rows + 2 B rows)
#define ISSUE_S(ss, nb)                                                      \
  do {                                                                       \
    const unsigned char* a_ = ((ss) < NKC ? Atg : Ahs) + Aoff                \
        + (size_t)((ss) & 15) * 8192 + (size_t)lane * 16;                    \
    const unsigned char* b_ = ((ss) < NKC ? Cbb : Wtb) + Boff                \
        + (size_t)((ss) & 15) * 8192 + (size_t)lane * 16;                    \
    load_lds16(a_ + w * 1024,       &sA[nb][w * 1024]);                      \
    load_lds16(a_ + (w + 4) * 1024, &sA[nb][(w + 4) * 1024]);                \
    load_lds16(b_ + w * 1024,       &sB[nb][w * 1024]);                      \
    load_lds16(b_ + (w + 4) * 1024, &sB[nb][(w + 4) * 1024]);                \
  } while (0)

  ISSUE_S(0, 0);
  ISSUE_S(1, 1);
  int cur = 0;
  #pragma unroll 1
  for (int s = 0; s < NSTG; ++s) {
    const int left = NSTG - 1 - s;
    if (left >= 2) {
      const int nb = (cur + 2 >= 3) ? cur - 1 : cur + 2;
      ISSUE_S(s + 2, nb);
      wait_vm8();                      // stage s landed; s+1, s+2 in flight
    } else if (left == 1) {
      wait_vm4();
    } else {
      wait_vm0();
    }
    barrier_raw();

    if (s == NKC) {
      // phase boundary: pack ct = cqc - 2*cross into bf16 pairs, reset acc
      #pragma unroll
      for (int mi = 0; mi < 2; ++mi)
        #pragma unroll
        for (int ni = 0; ni < 2; ++ni) {
          #pragma unroll
          for (int rp = 0; rp < 8; ++rp) {
            const float v0 = cqc[ni] - 2.f * acc[mi][ni][2 * rp];
            const float v1 = cqc[ni] - 2.f * acc[mi][ni][2 * rp + 1];
            ctp[mi][ni][rp] = (unsigned)f2bf(v0) | ((unsigned)f2bf(v1) << 16);
          }
          acc[mi][ni] = fz;
        }
    }

    {
      const int sb = (s < NKC) ? SB_UNIT : SB_W;
      const unsigned char* abase = &sA[cur][rb];
      const unsigned char* bbase = &sB[cur][rb];
      i32x8 aF[2], bF[2];
      #pragma unroll
      for (int mi = 0; mi < 2; ++mi) {
        i32x4 lo = *(const i32x4*)(abase + ((wr * 64 + mi * 32) << 4));
        i32x4 hh = *(const i32x4*)(abase + ((wr * 64 + mi * 32) << 4) + 2048);
        aF[mi] = __builtin_shufflevector(lo, hh, 0, 1, 2, 3, 4, 5, 6, 7);
      }
      #pragma unroll
      for (int ni = 0; ni < 2; ++ni) {
        i32x4 lo = *(const i32x4*)(bbase + ((wc * 64 + ni * 32) << 4));
        i32x4 hh = *(const i32x4*)(bbase + ((wc * 64 + ni * 32) << 4) + 2048);
        bF[ni] = __builtin_shufflevector(lo, hh, 0, 1, 2, 3, 4, 5, 6, 7);
      }
      #pragma unroll
      for (int mi = 0; mi < 2; ++mi)
        #pragma unroll
        for (int ni = 0; ni < 2; ++ni)
          acc[mi][ni] = __builtin_amdgcn_mfma_scale_f32_32x32x64_f8f6f4(
              aF[mi], bF[ni], acc[mi][ni], 0, 0, 0, SB_UNIT, 0, sb);
    }
    barrier_raw();
    cur = (cur + 1 >= 3) ? 0 : cur + 1;
  }
#undef ISSUE_S

  // ---------------- fused softmax epilogue per 64-col strip ----------------
  float bv[2];
  #pragma unroll
  for (int ni = 0; ni < 2; ++ni)
    bv[ni] = bias[tiley * NTILE + wc * 64 + ni * 32 + lc32];

  const int chunk = tiley * 2 + wc;
  #pragma unroll
  for (int mi = 0; mi < 2; ++mi) {
    #pragma unroll
    for (int r = 0; r < 16; ++r) {
      float lg[2], ct[2];
      #pragma unroll
      for (int ni = 0; ni < 2; ++ni) {
        lg[ni] = acc[mi][ni][r] + bv[ni];
        ct[ni] = bf2f((unsigned short)((ctp[mi][ni][r >> 1] >> ((r & 1) * 16)) & 0xFFFFu));
      }
      float tmax = fmaxf(lg[0], lg[1]);
      #pragma unroll
      for (int d = 1; d < 32; d <<= 1) tmax = fmaxf(tmax, __shfl_xor(tmax, d));
      float le = 0.f, se = 0.f;
      #pragma unroll
      for (int ni = 0; ni < 2; ++ni) {
        const float e = __expf(lg[ni] - tmax);
        le += e; se += e * ct[ni];
      }
      #pragma unroll
      for (int d = 1; d < 32; d <<= 1) {
        le += __shfl_xor(le, d);
        se += __shfl_xor(se, d);
      }
      if (lc32 == 0) {
        // 32x32 C/D: row = (r&3) + 8*(r>>2) + 4*(lane>>5), col = lane&31
        const int row = tilex * MT + wr * 64 + mi * 32 + 4 * hi32 + (r & 3) + 8 * (r >> 2);
        pm[chunk * NTOK + row] = tmax;
        pl[chunk * NTOK + row] = le;
        ps[chunk * NTOK + row] = se;
      }
    }
  }
}

// -------- merge strip partials -> scalar loss (last block finalizes) -------
// 128 blocks: 64 tokens x 4 strip-quarters per block; softmax partials
// (M,L,S) merge associatively: M=max Mi; L=sum Li e^{Mi-M}; S likewise.
__global__ __launch_bounds__(256) void k_merge(
    const int* __restrict__ counter, const float* __restrict__ tsq,
    const float* __restrict__ pm, const float* __restrict__ pl,
    const float* __restrict__ ps, float* __restrict__ lsum,
    int* __restrict__ done, float* __restrict__ out) {
  const int n = *counter;
  const int tl = threadIdx.x & 63, jq = threadIdx.x >> 6;
  const int ga = blockIdx.x * 64 + tl;
  float M = -1e30f, L = 0.f, S = 0.f;
  #pragma unroll 4
  for (int j = jq * 32; j < jq * 32 + 32; ++j) M = fmaxf(M, pm[j * NTOK + ga]);
  #pragma unroll 4
  for (int j = jq * 32; j < jq * 32 + 32; ++j) {
    const float e = __expf(pm[j * NTOK + ga] - M);
    L += pl[j * NTOK + ga] * e;
    S += ps[j * NTOK + ga] * e;
  }
  __shared__ float sM[4][64], sL[4][64], sS[4][64];
  sM[jq][tl] = M; sL[jq][tl] = L; sS[jq][tl] = S;
  __syncthreads();
  if (jq == 0) {
    float Mm = fmaxf(fmaxf(sM[0][tl], sM[1][tl]), fmaxf(sM[2][tl], sM[3][tl]));
    float Lt = 0.f, St = 0.f;
    #pragma unroll
    for (int q = 0; q < 4; ++q) {
      const float e = __expf(sM[q][tl] - Mm);
      Lt += sL[q][tl] * e;
      St += sS[q][tl] * e;
    }
    float val = 0.f;
    if (ga < n) val = (tsq[ga] + CTC + St / Lt) * (LOSSW / (float)H);
    #pragma unroll
    for (int d = 1; d < 64; d <<= 1) val += __shfl_xor(val, d);
    if (tl == 0) {
      atomicAdd(lsum, val);
      __threadfence();
      const int tk = atomicAdd(done, 1);
      if (tk == (int)gridDim.x - 1) {
        __threadfence();
        out[0] = atomicAdd(lsum, 0.0f);   // atomic read-back = final sum
      }
    }
  }
}

// ---------------------------------------------------------------------------
extern "C" void kernel_launch(void* const* d_in, const int* in_sizes, int n_in,
                              void* d_out, int out_size, void* d_ws, size_t ws_size,
                              hipStream_t stream) {
  const float* hs   = (const float*)d_in[0];
  const int*   ids  = (const int*)d_in[1];
  const float* tg   = (const float*)d_in[2];
  const float* cb   = (const float*)d_in[3];
  const float* W    = (const float*)d_in[4];
  const float* bias = (const float*)d_in[5];

  char* ws = (char*)d_ws;
  constexpr size_t OFF_CSQ  = 0;                       // f32[8192] (zeroed)
  constexpr size_t OFF_TSQ  = 32768;                   // f32[8192] (zeroed)
  constexpr size_t OFF_CNT  = 65536;                   // int (zeroed)
  constexpr size_t OFF_DONE = 65540;                   // int (zeroed)
  constexpr size_t OFF_LSUM = 65544;                   // f32 (zeroed)
  constexpr size_t ZERO_BYTES = 65548;
  constexpr size_t OFF_LIST = 65664;                   // int[8192]
  constexpr size_t OFF_AHS  = 98432;                   // fp8 slab 8 MiB
  constexpr size_t OFF_ATG  = OFF_AHS + (size_t)NTOK * H;
  constexpr size_t OFF_WTB  = OFF_ATG + (size_t)NTOK * H;
  constexpr size_t OFF_CBB  = OFF_WTB + (size_t)CBN * H;
  constexpr size_t OFF_PM   = OFF_CBB + (size_t)CBN * H;
  constexpr size_t OFF_PL   = OFF_PM + (size_t)NCHK * NTOK * 4;
  constexpr size_t OFF_PS   = OFF_PL + (size_t)NCHK * NTOK * 4;

  float*          csq  = (float*)(ws + OFF_CSQ);
  float*          tsq  = (float*)(ws + OFF_TSQ);
  int*            cnt  = (int*)(ws + OFF_CNT);
  int*            done = (int*)(ws + OFF_DONE);
  float*          lsum = (float*)(ws + OFF_LSUM);
  int*            list = (int*)(ws + OFF_LIST);
  unsigned char*  Ahs  = (unsigned char*)(ws + OFF_AHS);
  unsigned char*  Atg  = (unsigned char*)(ws + OFF_ATG);
  unsigned char*  Wtb  = (unsigned char*)(ws + OFF_WTB);
  unsigned char*  Cbb  = (unsigned char*)(ws + OFF_CBB);
  float*          pm   = (float*)(ws + OFF_PM);
  float*          pl   = (float*)(ws + OFF_PL);
  float*          ps   = (float*)(ws + OFF_PS);

  hipMemsetAsync(ws, 0, ZERO_BYTES, stream);

  k_compact<<<32, 256, 0, stream>>>(ids, list, cnt);
  k_prep_all<<<4096, 256, 0, stream>>>(hs, tg, cb, W, list, cnt, csq, tsq,
                                       Wtb, Cbb, Ahs, Atg);
  k_dual<<<dim3(64, 64), 256, 0, stream>>>(Atg, Cbb, Ahs, Wtb, csq, bias, cnt,
                                           pm, pl, ps);
  k_merge<<<NTOK / 64, 256, 0, stream>>>(cnt, tsq, pm, pl, ps, lsum, done,
                                         (float*)d_out);
}